// Round 2
// baseline (4057.678 us; speedup 1.0000x reference)
//
#include <hip/hip_runtime.h>
#include <hip/hip_bf16.h>
#include <cstdint>
#include <cstddef>

// Problem constants
#define R_DIM   128
#define R2_DIM  64
#define MIX     32
#define IN_DIM  512
#define HID     256
#define B_SZ    256
#define T_SZ    16
#define MAX_IT  12

// Workspace layout (float offsets). Total = 1,642,499 floats (~6.3 MiB).
#define OFF_G    0           // 128*128
#define OFF_U    16384       // 4096*128
#define OFF_SX   540672      // 4096
#define OFF_C    544768      // 256*4096
#define OFF_R    1593344     // 256*128
#define OFF_R2   1626112     // 256*64
#define OFF_LOSS 1642496     // 3

__device__ __forceinline__ float softt(float v, float lam) {
  float a = fabsf(v) - lam;
  return a > 0.f ? (v > 0.f ? a : -a) : 0.f;
}

// ---------------- init: zero r, r2, loss accumulators (ws is poisoned 0xAA) ---
__global__ __launch_bounds__(256) void k_init(float* ws) {
  int idx = blockIdx.x * blockDim.x + threadIdx.x;
  const int n = B_SZ * R_DIM + B_SZ * R2_DIM + 3;  // contiguous from OFF_R
  for (int i = idx; i < n; i += gridDim.x * blockDim.x) ws[OFF_R + i] = 0.f;
}

// ---------------- G = dec_W @ dec_W^T (128x128) -------------------------------
__global__ __launch_bounds__(128) void k_prepG(const float* __restrict__ decW,
                                               float* __restrict__ G) {
  __shared__ __align__(16) float rowi[IN_DIM];
  int i = blockIdx.x;
  for (int d = threadIdx.x; d < IN_DIM; d += 128) rowi[d] = decW[i * IN_DIM + d];
  __syncthreads();
  int j = threadIdx.x;
  const float* wr = decW + (size_t)j * IN_DIM;
  float acc = 0.f;
  for (int d4 = 0; d4 < IN_DIM / 4; d4++) {
    float4 w4 = *reinterpret_cast<const float4*>(wr + d4 * 4);
    float4 r4 = *reinterpret_cast<const float4*>(&rowi[d4 * 4]);
    acc += w4.x * r4.x + w4.y * r4.y + w4.z * r4.z + w4.w * r4.w;
  }
  G[i * R_DIM + j] = acc;
}

// ---------------- u[b,t,:] = (x - dec_b) @ dec_W^T ; sx[b,t] = ||x-dec_b||^2 --
// 8 (b,t) rows per block to amortize the dec_W stream.
__global__ __launch_bounds__(128) void k_prepU(const float* __restrict__ X,
                                               const float* __restrict__ decb,
                                               const float* __restrict__ decW,
                                               float* __restrict__ U,
                                               float* __restrict__ SX) {
  __shared__ __align__(16) float xm[8][IN_DIM];
  __shared__ float scr[128];
  int blk0 = blockIdx.x * 8;
  for (int p = threadIdx.x; p < 8 * IN_DIM / 4; p += 128) {  // float4 units
    int g = p >> 7, c4 = p & 127;
    float4 xv = *reinterpret_cast<const float4*>(X + (size_t)(blk0 + g) * IN_DIM + c4 * 4);
    float4 bv = *reinterpret_cast<const float4*>(decb + c4 * 4);
    xm[g][c4 * 4 + 0] = xv.x - bv.x;
    xm[g][c4 * 4 + 1] = xv.y - bv.y;
    xm[g][c4 * 4 + 2] = xv.z - bv.z;
    xm[g][c4 * 4 + 3] = xv.w - bv.w;
  }
  __syncthreads();
  {  // sx
    int g = threadIdx.x >> 4, l16 = threadIdx.x & 15;
    float s = 0.f;
    for (int dd = 0; dd < 32; dd++) { float v = xm[g][l16 * 32 + dd]; s += v * v; }
    scr[threadIdx.x] = s;
  }
  __syncthreads();
  if (threadIdx.x < 8) {
    float s = 0.f;
    for (int h = 0; h < 16; h++) s += scr[threadIdx.x * 16 + h];
    SX[blk0 + threadIdx.x] = s;
  }
  // u: thread i streams dec_W row i once, 8 accumulators
  int i = threadIdx.x;
  const float* wr = decW + (size_t)i * IN_DIM;
  float acc[8] = {0.f, 0.f, 0.f, 0.f, 0.f, 0.f, 0.f, 0.f};
  for (int d4 = 0; d4 < IN_DIM / 4; d4++) {
    float4 w4 = *reinterpret_cast<const float4*>(wr + d4 * 4);
#pragma unroll
    for (int g = 0; g < 8; g++) {
      float4 xv = *reinterpret_cast<const float4*>(&xm[g][d4 * 4]);
      acc[g] += w4.x * xv.x + w4.y * xv.y + w4.z * xv.z + w4.w * xv.w;
    }
  }
  for (int g = 0; g < 8; g++) U[(size_t)(blk0 + g) * R_DIM + i] = acc[g];
}

// ---------------- c[b, mi] = sum_j T2[mi, j] * r_prev[b, j] -------------------
// T2 = temporal viewed as (4096, 128). Tiled GEMM: 64 mi x 64 b per block,
// j-dim staged in two halves to stay < 64 KB LDS.
__global__ __launch_bounds__(256) void k_c(const float* __restrict__ T2,
                                           const float* __restrict__ Rg,
                                           float* __restrict__ Cg) {
  __shared__ __align__(16) float Al[64 * 68];  // r rows   [b][j-half]
  __shared__ __align__(16) float Bl[64 * 68];  // T2 rows  [mi][j-half]
  int mi0 = blockIdx.x * 64, b0 = blockIdx.y * 64;
  int t = threadIdx.x;
  int tb = t & 15, tm = t >> 4;
  float acc[4][4];
#pragma unroll
  for (int a = 0; a < 4; a++)
#pragma unroll
    for (int c = 0; c < 4; c++) acc[a][c] = 0.f;
  for (int h = 0; h < 2; h++) {
    __syncthreads();
    for (int p = t; p < 64 * 16; p += 256) {  // float4 units
      int row = p >> 4, c4 = p & 15;
      *reinterpret_cast<float4*>(Al + row * 68 + c4 * 4) =
          *reinterpret_cast<const float4*>(Rg + (size_t)(b0 + row) * R_DIM + h * 64 + c4 * 4);
      *reinterpret_cast<float4*>(Bl + row * 68 + c4 * 4) =
          *reinterpret_cast<const float4*>(T2 + (size_t)(mi0 + row) * R_DIM + h * 64 + c4 * 4);
    }
    __syncthreads();
    for (int jc = 0; jc < 16; jc++) {
      float4 av[4], bv[4];
#pragma unroll
      for (int bb = 0; bb < 4; bb++)
        av[bb] = *reinterpret_cast<const float4*>(Al + (tb + 16 * bb) * 68 + jc * 4);
#pragma unroll
      for (int ii = 0; ii < 4; ii++)
        bv[ii] = *reinterpret_cast<const float4*>(Bl + (tm * 4 + ii) * 68 + jc * 4);
#pragma unroll
      for (int bb = 0; bb < 4; bb++)
#pragma unroll
        for (int ii = 0; ii < 4; ii++)
          acc[bb][ii] += av[bb].x * bv[ii].x + av[bb].y * bv[ii].y +
                         av[bb].z * bv[ii].z + av[bb].w * bv[ii].w;
    }
  }
#pragma unroll
  for (int bb = 0; bb < 4; bb++)
#pragma unroll
    for (int ii = 0; ii < 4; ii++)
      Cg[(size_t)(b0 + tb + 16 * bb) * (MIX * R_DIM) + mi0 + tm * 4 + ii] = acc[bb][ii];
}

// ---------------- ISTA step kernel (one block per batch element) --------------
struct __align__(16) SM {
  float c[MIX * 129];  // padded stride 129: conflict-free for both access modes
  float uL[R_DIM];
  float rL[R_DIM];
  float r2L[R2_DIM];
  float aL[HID];
  float x2L[HID];
  float eL[R_DIM];
  float rhfL[R_DIM];
  float gspL[R_DIM];
  float wL[MIX];
  float dx3L[MIX];
  float dx2L[HID];
  float dx1L[HID];
  float scr[HID];
  float red[8];
  float sxS;
};

__device__ __forceinline__ float2 blk_sum2(float a, float b, float* red) {
  __syncthreads();  // protect red from previous readers
#pragma unroll
  for (int off = 32; off > 0; off >>= 1) {
    a += __shfl_down(a, off, 64);
    b += __shfl_down(b, off, 64);
  }
  int wid = threadIdx.x >> 6, lane = threadIdx.x & 63;
  if (lane == 0) { red[wid] = a; red[4 + wid] = b; }
  __syncthreads();
  return make_float2(red[0] + red[1] + red[2] + red[3],
                     red[4] + red[5] + red[6] + red[7]);
}

// Hypernet forward from s.r2L. Persists per-thread (xhat, a, rstd) for backward.
__device__ __forceinline__ void hyp_fwd(SM& s, const float* __restrict__ h1W,
                                        const float* __restrict__ h2W,
                                        const float* __restrict__ h3W,
                                        const float* __restrict__ h3b,
                                        float h1bj, float h2bj, float lnsj, float lnbj,
                                        float& xhatj, float& aj, float& rstd) {
  int j = threadIdx.x;
  float x1 = h1bj;
#pragma unroll 4
  for (int k4 = 0; k4 < R2_DIM / 4; k4++) {
    float4 r4 = *reinterpret_cast<const float4*>(&s.r2L[k4 * 4]);
    int kb = k4 * 4;
    x1 += r4.x * h1W[(kb + 0) * HID + j] + r4.y * h1W[(kb + 1) * HID + j] +
          r4.z * h1W[(kb + 2) * HID + j] + r4.w * h1W[(kb + 3) * HID + j];
  }
  float2 s12 = blk_sum2(x1, x1 * x1, s.red);
  float mu = s12.x * (1.f / HID);
  float var = s12.y * (1.f / HID) - mu * mu;
  rstd = rsqrtf(var + 1e-6f);
  xhatj = (x1 - mu) * rstd;
  float y = xhatj * lnsj + lnbj;
  aj = (y > 0.f) ? y : expm1f(y);
  s.aL[j] = aj;
  __syncthreads();
  float x2 = h2bj;
#pragma unroll 4
  for (int k4 = 0; k4 < HID / 4; k4++) {
    float4 a4 = *reinterpret_cast<const float4*>(&s.aL[k4 * 4]);
    int kb = k4 * 4;
    x2 += a4.x * h2W[(kb + 0) * HID + j] + a4.y * h2W[(kb + 1) * HID + j] +
          a4.z * h2W[(kb + 2) * HID + j] + a4.w * h2W[(kb + 3) * HID + j];
  }
  s.x2L[j] = x2;
  __syncthreads();
  {  // x3 = x2 @ h3W + b3 ; w = relu(x3). Chunked over 8 k-groups.
    int mm = j & 31, q = j >> 5;
    float p = 0.f;
#pragma unroll 4
    for (int kk = 0; kk < 32; kk++) p += s.x2L[q * 32 + kk] * h3W[(q * 32 + kk) * MIX + mm];
    s.scr[j] = p;
    __syncthreads();
    if (j < MIX) {
      float v = h3b[j];
#pragma unroll
      for (int h = 0; h < 8; h++) v += s.scr[j + 32 * h];
      s.wL[j] = fmaxf(v, 0.f);
    }
  }
  __syncthreads();
}

// Hypernet backward from s.eL; updates s.r2L with proximal step.
__device__ __forceinline__ void hyp_bwd(SM& s, const float* __restrict__ h1W,
                                        const float* __restrict__ h2W,
                                        const float* __restrict__ h3W,
                                        float xhatj, float aj, float rstd, float lnsj) {
  int t = threadIdx.x;
  {  // dw[m] = -2 * sum_i e_i * c[m,i]  (chunked 8x16)
    int m = t & 31, ih = t >> 5;
    float p = 0.f;
#pragma unroll 4
    for (int q = 0; q < 16; q++) { int i = ih * 16 + q; p += s.eL[i] * s.c[m * 129 + i]; }
    s.scr[t] = p;
  }
  __syncthreads();
  if (t < MIX) {
    float v = 0.f;
#pragma unroll
    for (int h = 0; h < 8; h++) v += s.scr[t + 32 * h];
    s.dx3L[t] = (s.wL[t] > 0.f) ? (-2.f * v) : 0.f;  // relu mask
  }
  __syncthreads();
  float dx2 = 0.f;
  {  // dx2 = dx3 @ h3W^T  (per-thread contiguous row of h3W)
    const float* row = h3W + (size_t)t * MIX;
#pragma unroll
    for (int m4 = 0; m4 < MIX / 4; m4++) {
      float4 d4 = *reinterpret_cast<const float4*>(&s.dx3L[m4 * 4]);
      float4 w4 = *reinterpret_cast<const float4*>(row + m4 * 4);
      dx2 += d4.x * w4.x + d4.y * w4.y + d4.z * w4.z + d4.w * w4.w;
    }
  }
  s.dx2L[t] = dx2;
  __syncthreads();
  float da = 0.f;
  {  // da = dx2 @ h2W^T  (per-thread contiguous row of h2W, L1-window friendly)
    const float* row = h2W + (size_t)t * HID;
#pragma unroll 4
    for (int j4 = 0; j4 < HID / 4; j4++) {
      float4 d4 = *reinterpret_cast<const float4*>(&s.dx2L[j4 * 4]);
      float4 w4 = *reinterpret_cast<const float4*>(row + j4 * 4);
      da += d4.x * w4.x + d4.y * w4.y + d4.z * w4.z + d4.w * w4.w;
    }
  }
  // ELU' (a>0 <=> y>0; else e^y = a+1), then LayerNorm backward
  float dy = da * (aj > 0.f ? 1.f : (aj + 1.f));
  float dxh = dy * lnsj;
  float2 s12 = blk_sum2(dxh, dxh * xhatj, s.red);
  float dx1 = rstd * (dxh - s12.x * (1.f / HID) - xhatj * (s12.y * (1.f / HID)));
  s.dx1L[t] = dx1;
  __syncthreads();
  {  // dr2[k] = sum_j dx1[j] * h1W[k,j]  (chunked 64x4)
    int k2 = t >> 2, q = t & 3;
    const float* row = h1W + (size_t)k2 * HID + q * 64;
    float p = 0.f;
#pragma unroll 4
    for (int j4 = 0; j4 < 16; j4++) {
      float4 d4 = *reinterpret_cast<const float4*>(&s.dx1L[q * 64 + j4 * 4]);
      float4 w4 = *reinterpret_cast<const float4*>(row + j4 * 4);
      p += d4.x * w4.x + d4.y * w4.y + d4.z * w4.z + d4.w * w4.w;
    }
    s.scr[t] = p;
  }
  __syncthreads();
  if (t < R2_DIM) {
    float g = s.scr[4 * t] + s.scr[4 * t + 1] + s.scr[4 * t + 2] + s.scr[4 * t + 3];
    s.r2L[t] = softt(s.r2L[t] - 0.1f * g, 0.001f);
  }
  __syncthreads();
}

__device__ __forceinline__ float rhat_at(SM& s, int i) {
  float rh = 0.f;
#pragma unroll
  for (int m4 = 0; m4 < MIX / 4; m4++) {
    float4 w4 = *reinterpret_cast<const float4*>(&s.wL[m4 * 4]);
    int mb = m4 * 4;
    rh += w4.x * s.c[(mb + 0) * 129 + i] + w4.y * s.c[(mb + 1) * 129 + i] +
          w4.z * s.c[(mb + 2) * 129 + i] + w4.w * s.c[(mb + 3) * 129 + i];
  }
  return rh;
}

__global__ __launch_bounds__(256) void k_ista(float* __restrict__ ws,
                                              const float* __restrict__ h1W,
                                              const float* __restrict__ h1b,
                                              const float* __restrict__ lns,
                                              const float* __restrict__ lnb,
                                              const float* __restrict__ h2W,
                                              const float* __restrict__ h2b,
                                              const float* __restrict__ h3W,
                                              const float* __restrict__ h3b,
                                              int tstep) {
  const float* Gm = ws + OFF_G;
  const float* U = ws + OFF_U;
  const float* SXg = ws + OFF_SX;
  const float* Cg = ws + OFF_C;
  float* Rg = ws + OFF_R;
  float* R2g = ws + OFF_R2;
  float* Lacc = ws + OFF_LOSS;

  int b = blockIdx.x, t = threadIdx.x;
  int blk = b * T_SZ + tstep;
  __shared__ SM s;

  // stage c (scalar writes; padded stride 129), u, r2, sx
  for (int p = t; p < MIX * R_DIM; p += 256)
    s.c[(p >> 7) * 129 + (p & 127)] = Cg[(size_t)b * (MIX * R_DIM) + p];
  if (t < R_DIM) s.uL[t] = U[(size_t)blk * R_DIM + t];
  if (t < R2_DIM) s.r2L[t] = R2g[b * R2_DIM + t];
  if (t == 0) s.sxS = SXg[blk];
  float lnsj = lns[t], lnbj = lnb[t], h1bj = h1b[t], h2bj = h2b[t];
  __syncthreads();

  float xhatj, aj, rstd;
  hyp_fwd(s, h1W, h2W, h3W, h3b, h1bj, h2bj, lnsj, lnbj, xhatj, aj, rstd);

  // warm start: r0 = w(r2) . c   (no soft-threshold, matches reference)
  if (t < R_DIM) s.rL[t] = rhat_at(s, t);
  __syncthreads();

  for (int it = 0; it < MAX_IT; it++) {
    // [A] waves 0-1: r_hat & e ; waves 2-3: r @ G
    if (t < R_DIM) {
      s.eL[t] = s.rL[t] - rhat_at(s, t);
    } else {
      int i = t - R_DIM;
      float g = 0.f;
#pragma unroll 4
      for (int j4 = 0; j4 < R_DIM / 4; j4++) {
        float4 r4 = *reinterpret_cast<const float4*>(&s.rL[j4 * 4]);
        int jb = j4 * 4;
        g += r4.x * Gm[(jb + 0) * R_DIM + i] + r4.y * Gm[(jb + 1) * R_DIM + i] +
             r4.z * Gm[(jb + 2) * R_DIM + i] + r4.w * Gm[(jb + 3) * R_DIM + i];
      }
      s.gspL[i] = g;
    }
    __syncthreads();
    // [B] proximal update of r (grads at old (r, r2))
    if (t < R_DIM) {
      float gr = 2.f * (s.gspL[t] - s.uL[t]) + 2.f * s.eL[t];
      s.rL[t] = softt(s.rL[t] - 0.1f * gr, 0.001f);
    }
    // backward (uses e at old r) -> updates r2 ; forward -> w(new r2)
    hyp_bwd(s, h1W, h2W, h3W, xhatj, aj, rstd, lnsj);
    hyp_fwd(s, h1W, h2W, h3W, h3b, h1bj, h2bj, lnsj, lnbj, xhatj, aj, rstd);
  }

  // final r_hat with w(r2_final), losses via quadratic form
  if (t < R_DIM) s.rhfL[t] = rhat_at(s, t);
  __syncthreads();
  float c0 = 0.f, c1 = 0.f, c2 = 0.f;
  if (t < R_DIM) {
    float g = 0.f;
#pragma unroll 4
    for (int j4 = 0; j4 < R_DIM / 4; j4++) {
      float4 r4 = *reinterpret_cast<const float4*>(&s.rhfL[j4 * 4]);
      int jb = j4 * 4;
      g += r4.x * Gm[(jb + 0) * R_DIM + t] + r4.y * Gm[(jb + 1) * R_DIM + t] +
           r4.z * Gm[(jb + 2) * R_DIM + t] + r4.w * Gm[(jb + 3) * R_DIM + t];
    }
    float v = s.rhfL[t];
    c0 = v * g - 2.f * v * s.uL[t];
    float e = s.rL[t] - v;
    c2 = e * e;
  } else {
    int i = t - R_DIM;
    float g = 0.f;
#pragma unroll 4
    for (int j4 = 0; j4 < R_DIM / 4; j4++) {
      float4 r4 = *reinterpret_cast<const float4*>(&s.rL[j4 * 4]);
      int jb = j4 * 4;
      g += r4.x * Gm[(jb + 0) * R_DIM + i] + r4.y * Gm[(jb + 1) * R_DIM + i] +
           r4.z * Gm[(jb + 2) * R_DIM + i] + r4.w * Gm[(jb + 3) * R_DIM + i];
    }
    float v = s.rL[i];
    c1 = v * g - 2.f * v * s.uL[i];
  }
  float2 s01 = blk_sum2(c0, c1, s.red);
  float2 s2x = blk_sum2(c2, 0.f, s.red);
  if (t == 0) {
    atomicAdd(&Lacc[0], s01.x + s.sxS);  // spat_rhat
    atomicAdd(&Lacc[1], s01.y + s.sxS);  // spat_rbar
    atomicAdd(&Lacc[2], s2x.x);          // temp_loss
  }
  if (t < R_DIM) Rg[b * R_DIM + t] = s.rL[t];
  if (t < R2_DIM) R2g[b * R2_DIM + t] = s.r2L[t];
}

// ---------------- finalize: fp32 outputs (reference output dtype is float32) --
__global__ __launch_bounds__(256) void k_final(const float* __restrict__ ws,
                                               float* __restrict__ out) {
  int idx = blockIdx.x * 256 + threadIdx.x;
  const int n = 3 + B_SZ * R_DIM + B_SZ * R2_DIM;
  if (idx >= n) return;
  float v;
  if (idx < 3) v = ws[OFF_LOSS + idx] * (1.f / (B_SZ * T_SZ));
  else if (idx < 3 + B_SZ * R_DIM) v = ws[OFF_R + (idx - 3)];
  else v = ws[OFF_R2 + (idx - 3 - B_SZ * R_DIM)];
  out[idx] = v;
}

extern "C" void kernel_launch(void* const* d_in, const int* in_sizes, int n_in,
                              void* d_out, int out_size, void* d_ws, size_t ws_size,
                              hipStream_t stream) {
  const float* X = (const float*)d_in[0];
  const float* decW = (const float*)d_in[1];
  const float* decb = (const float*)d_in[2];
  const float* temporal = (const float*)d_in[3];
  const float* h1W = (const float*)d_in[4];
  const float* h1b = (const float*)d_in[5];
  const float* lns = (const float*)d_in[6];
  const float* lnb = (const float*)d_in[7];
  const float* h2W = (const float*)d_in[8];
  const float* h2b = (const float*)d_in[9];
  const float* h3W = (const float*)d_in[10];
  const float* h3b = (const float*)d_in[11];
  float* ws = (float*)d_ws;  // needs ~6.3 MiB
  float* out = (float*)d_out;

  k_init<<<64, 256, 0, stream>>>(ws);
  k_prepG<<<128, 128, 0, stream>>>(decW, ws + OFF_G);
  k_prepU<<<512, 128, 0, stream>>>(X, decb, decW, ws + OFF_U, ws + OFF_SX);
  for (int t = 0; t < T_SZ; t++) {
    k_c<<<dim3(64, 4), 256, 0, stream>>>(temporal, ws + OFF_R, ws + OFF_C);
    k_ista<<<B_SZ, 256, 0, stream>>>(ws, h1W, h1b, lns, lnb, h2W, h2b, h3W, h3b, t);
  }
  k_final<<<193, 256, 0, stream>>>(ws, out);
}

// Round 3
// 723.508 us; speedup vs baseline: 5.6083x; 5.6083x over previous
//
#include <hip/hip_runtime.h>
#include <cstdint>
#include <cstddef>

// Problem constants
#define R_DIM   128
#define R2_DIM  64
#define MIX     32
#define IN_DIM  512
#define HID     256
#define B_SZ    256
#define T_SZ    16
#define MAX_IT  12

// Workspace layout (float offsets). Total = 593,923 floats (~2.3 MiB).
#define OFF_G    0           // 128*128
#define OFF_U    16384       // 4096*128
#define OFF_SX   540672      // 4096
#define OFF_R    544768      // 256*128
#define OFF_R2   577536      // 256*64
#define OFF_LOSS 593920      // 3

__device__ __forceinline__ float softt(float v, float lam) {
  float a = fabsf(v) - lam;
  return a > 0.f ? (v > 0.f ? a : -a) : 0.f;
}

// ---------------- init: zero r, r2, loss accumulators -------------------------
__global__ __launch_bounds__(256) void k_init(float* ws) {
  int idx = blockIdx.x * blockDim.x + threadIdx.x;
  const int n = B_SZ * R_DIM + B_SZ * R2_DIM + 3;  // contiguous from OFF_R
  for (int i = idx; i < n; i += gridDim.x * blockDim.x) ws[OFF_R + i] = 0.f;
}

// ---------------- G = dec_W @ dec_W^T (128x128, symmetric) --------------------
__global__ __launch_bounds__(128) void k_prepG(const float* __restrict__ decW,
                                               float* __restrict__ G) {
  __shared__ __align__(16) float rowi[IN_DIM];
  int i = blockIdx.x;
  for (int d = threadIdx.x; d < IN_DIM; d += 128) rowi[d] = decW[i * IN_DIM + d];
  __syncthreads();
  int j = threadIdx.x;
  const float* wr = decW + (size_t)j * IN_DIM;
  float acc = 0.f;
  for (int d4 = 0; d4 < IN_DIM / 4; d4++) {
    float4 w4 = *reinterpret_cast<const float4*>(wr + d4 * 4);
    float4 r4 = *reinterpret_cast<const float4*>(&rowi[d4 * 4]);
    acc += w4.x * r4.x + w4.y * r4.y + w4.z * r4.z + w4.w * r4.w;
  }
  G[i * R_DIM + j] = acc;
}

// ---------------- u[b,t,:] = (x - dec_b) @ dec_W^T ; sx[b,t] = ||x-dec_b||^2 --
__global__ __launch_bounds__(128) void k_prepU(const float* __restrict__ X,
                                               const float* __restrict__ decb,
                                               const float* __restrict__ decW,
                                               float* __restrict__ U,
                                               float* __restrict__ SX) {
  __shared__ __align__(16) float xm[8][IN_DIM];
  __shared__ float scr[128];
  int blk0 = blockIdx.x * 8;
  for (int p = threadIdx.x; p < 8 * IN_DIM / 4; p += 128) {
    int g = p >> 7, c4 = p & 127;
    float4 xv = *reinterpret_cast<const float4*>(X + (size_t)(blk0 + g) * IN_DIM + c4 * 4);
    float4 bv = *reinterpret_cast<const float4*>(decb + c4 * 4);
    xm[g][c4 * 4 + 0] = xv.x - bv.x;
    xm[g][c4 * 4 + 1] = xv.y - bv.y;
    xm[g][c4 * 4 + 2] = xv.z - bv.z;
    xm[g][c4 * 4 + 3] = xv.w - bv.w;
  }
  __syncthreads();
  {
    int g = threadIdx.x >> 4, l16 = threadIdx.x & 15;
    float s = 0.f;
    for (int dd = 0; dd < 32; dd++) { float v = xm[g][l16 * 32 + dd]; s += v * v; }
    scr[threadIdx.x] = s;
  }
  __syncthreads();
  if (threadIdx.x < 8) {
    float s = 0.f;
    for (int h = 0; h < 16; h++) s += scr[threadIdx.x * 16 + h];
    SX[blk0 + threadIdx.x] = s;
  }
  int i = threadIdx.x;
  const float* wr = decW + (size_t)i * IN_DIM;
  float acc[8] = {0.f, 0.f, 0.f, 0.f, 0.f, 0.f, 0.f, 0.f};
  for (int d4 = 0; d4 < IN_DIM / 4; d4++) {
    float4 w4 = *reinterpret_cast<const float4*>(wr + d4 * 4);
#pragma unroll
    for (int g = 0; g < 8; g++) {
      float4 xv = *reinterpret_cast<const float4*>(&xm[g][d4 * 4]);
      acc[g] += w4.x * xv.x + w4.y * xv.y + w4.z * xv.z + w4.w * xv.w;
    }
  }
  for (int g = 0; g < 8; g++) U[(size_t)(blk0 + g) * R_DIM + i] = acc[g];
}

// ---------------- ISTA step kernel (one block per batch element) --------------
struct __align__(16) SMS {
  float uL[R_DIM], rL[R_DIM], rprevL[R_DIM], eL[R_DIM], rhfL[R_DIM];
  float r2L[R2_DIM];
  float aL[HID], x2L[HID], dx2L[HID], dx1L[HID], scr[HID];
  float wL[MIX], dx3L[MIX];
  float red[8];
  int vz[12];     // 3 vote slots x 4 waves
  int cst;        // c staged?
  float sxS;
};

// swizzled float4 index into gG: row i (0..127), chunk c (0..31)
__device__ __forceinline__ int gsw(int i, int c) { return (i * 32 + (c ^ (i & 31))) * 4; }

// block-uniform "any nonzero" vote; slot in {0,4,8}
__device__ __forceinline__ bool vote_nz(bool my_nz, int* vz) {
  unsigned long long m = __ballot(my_nz);
  if ((threadIdx.x & 63) == 0) vz[threadIdx.x >> 6] = (m != 0ull) ? 1 : 0;
  __syncthreads();
  return (vz[0] | vz[1] | vz[2] | vz[3]) != 0;
}

__device__ __forceinline__ float2 blk_sum2(float a, float b, float* red) {
  __syncthreads();
#pragma unroll
  for (int off = 32; off > 0; off >>= 1) {
    a += __shfl_down(a, off, 64);
    b += __shfl_down(b, off, 64);
  }
  int wid = threadIdx.x >> 6, lane = threadIdx.x & 63;
  if (lane == 0) { red[wid] = a; red[4 + wid] = b; }
  __syncthreads();
  return make_float2(red[0] + red[1] + red[2] + red[3],
                     red[4] + red[5] + red[6] + red[7]);
}

// lazy per-block c[m,i] = sum_j temporal[m*128+i][j] * r_prev[j]
__device__ void ensure_c(SMS& s, float* cS, const float* __restrict__ T2, int t) {
  if (s.cst) return;  // uniform
  for (int p = t; p < MIX * R_DIM; p += 256) {
    const float* row = T2 + (size_t)p * R_DIM;
    float acc = 0.f;
#pragma unroll 8
    for (int j4 = 0; j4 < R_DIM / 4; j4++) {
      float4 w4 = *reinterpret_cast<const float4*>(row + j4 * 4);
      float4 r4 = *reinterpret_cast<const float4*>(&s.rprevL[j4 * 4]);
      acc += w4.x * r4.x + w4.y * r4.y + w4.z * r4.z + w4.w * r4.w;
    }
    cS[(p >> 7) * 129 + (p & 127)] = acc;
  }
  if (t == 0) s.cst = 1;
  __syncthreads();
}

__device__ __forceinline__ float rhat_at(SMS& s, const float* cS, int i) {
  float rh = 0.f;
#pragma unroll
  for (int m4 = 0; m4 < MIX / 4; m4++) {
    float4 w4 = *reinterpret_cast<const float4*>(&s.wL[m4 * 4]);
    int mb = m4 * 4;
    rh += w4.x * cS[(mb + 0) * 129 + i] + w4.y * cS[(mb + 1) * 129 + i] +
          w4.z * cS[(mb + 2) * 129 + i] + w4.w * cS[(mb + 3) * 129 + i];
  }
  return rh;
}

// hypernet forward; zr2 in, zw out; persists per-thread (xhat, a, rstd)
__device__ void hyp_fwd(SMS& s, const float* __restrict__ h1W,
                        const float* __restrict__ h2W,
                        const float* __restrict__ h3W,
                        const float* __restrict__ h3b,
                        float h1bj, float h2bj, float lnsj, float lnbj,
                        bool zr2, bool& zw, float& xhatj, float& aj, float& rstd) {
  int j = threadIdx.x;
  float x1 = h1bj;
  if (!zr2) {
#pragma unroll 4
    for (int k4 = 0; k4 < R2_DIM / 4; k4++) {
      float4 r4 = *reinterpret_cast<const float4*>(&s.r2L[k4 * 4]);
      int kb = k4 * 4;
      x1 += r4.x * h1W[(kb + 0) * HID + j] + r4.y * h1W[(kb + 1) * HID + j] +
            r4.z * h1W[(kb + 2) * HID + j] + r4.w * h1W[(kb + 3) * HID + j];
    }
  }
  float2 s12 = blk_sum2(x1, x1 * x1, s.red);
  float mu = s12.x * (1.f / HID);
  float var = s12.y * (1.f / HID) - mu * mu;
  rstd = rsqrtf(var + 1e-6f);
  xhatj = (x1 - mu) * rstd;
  float y = xhatj * lnsj + lnbj;
  aj = (y > 0.f) ? y : expm1f(y);
  s.aL[j] = aj;
  bool za = !vote_nz(aj != 0.f, s.vz + 4);   // slot1 (barrier inside)
  float x2 = h2bj;
  if (!za) {
#pragma unroll 4
    for (int k4 = 0; k4 < HID / 4; k4++) {
      float4 a4 = *reinterpret_cast<const float4*>(&s.aL[k4 * 4]);
      int kb = k4 * 4;
      x2 += a4.x * h2W[(kb + 0) * HID + j] + a4.y * h2W[(kb + 1) * HID + j] +
            a4.z * h2W[(kb + 2) * HID + j] + a4.w * h2W[(kb + 3) * HID + j];
    }
  }
  s.x2L[j] = x2;
  bool zx2 = !vote_nz(x2 != 0.f, s.vz + 8);  // slot2
  float wv = 0.f;
  if (!zx2) {
    int mm = j & 31, q = j >> 5;
    float p = 0.f;
#pragma unroll 4
    for (int kk = 0; kk < 32; kk++) p += s.x2L[q * 32 + kk] * h3W[(q * 32 + kk) * MIX + mm];
    s.scr[j] = p;
    __syncthreads();
    if (j < MIX) {
      float v = h3b[j];
#pragma unroll
      for (int h = 0; h < 8; h++) v += s.scr[j + 32 * h];
      wv = fmaxf(v, 0.f);
      s.wL[j] = wv;
    }
  } else {
    if (j < MIX) { wv = fmaxf(h3b[j], 0.f); s.wL[j] = wv; }
  }
  zw = !vote_nz((j < MIX) && (wv != 0.f), s.vz + 0);  // slot0
}

// hypernet backward from s.eL; proximal r2 update; zr2_out
__device__ void hyp_bwd(SMS& s, float* cS, const float* __restrict__ T2,
                        const float* __restrict__ h1W,
                        const float* __restrict__ h2W,
                        const float* __restrict__ h3W,
                        bool zw, bool& zr2_out,
                        float xhatj, float aj, float rstd, float lnsj) {
  int t = threadIdx.x;
  bool zd3;
  if (!zw) {
    ensure_c(s, cS, T2, t);
    __syncthreads();  // protect scr from iterB readers
    {
      int m = t & 31, ih = t >> 5;
      float p = 0.f;
#pragma unroll 4
      for (int q = 0; q < 16; q++) { int i = ih * 16 + q; p += s.eL[i] * cS[m * 129 + i]; }
      s.scr[t] = p;
    }
    __syncthreads();
    float d3 = 0.f;
    if (t < MIX) {
      float v = 0.f;
#pragma unroll
      for (int h = 0; h < 8; h++) v += s.scr[t + 32 * h];
      d3 = (s.wL[t] > 0.f) ? (-2.f * v) : 0.f;
      s.dx3L[t] = d3;
    }
    zd3 = !vote_nz((t < MIX) && (d3 != 0.f), s.vz + 4);  // slot1
  } else {
    zd3 = true;
  }
  float g = 0.f;
  if (!zd3) {
    float dx2 = 0.f;
    {
      const float* row = h3W + (size_t)t * MIX;
#pragma unroll
      for (int m4 = 0; m4 < MIX / 4; m4++) {
        float4 d4 = *reinterpret_cast<const float4*>(&s.dx3L[m4 * 4]);
        float4 w4 = *reinterpret_cast<const float4*>(row + m4 * 4);
        dx2 += d4.x * w4.x + d4.y * w4.y + d4.z * w4.z + d4.w * w4.w;
      }
    }
    s.dx2L[t] = dx2;
    __syncthreads();
    float da = 0.f;
    {
      const float* row = h2W + (size_t)t * HID;
#pragma unroll 4
      for (int j4 = 0; j4 < HID / 4; j4++) {
        float4 d4 = *reinterpret_cast<const float4*>(&s.dx2L[j4 * 4]);
        float4 w4 = *reinterpret_cast<const float4*>(row + j4 * 4);
        da += d4.x * w4.x + d4.y * w4.y + d4.z * w4.z + d4.w * w4.w;
      }
    }
    float dy = da * (aj > 0.f ? 1.f : (aj + 1.f));
    float dxh = dy * lnsj;
    float2 s12 = blk_sum2(dxh, dxh * xhatj, s.red);
    float dx1 = rstd * (dxh - s12.x * (1.f / HID) - xhatj * (s12.y * (1.f / HID)));
    s.dx1L[t] = dx1;
    __syncthreads();
    {
      int k2 = t >> 2, q = t & 3;
      const float* row = h1W + (size_t)k2 * HID + q * 64;
      float p = 0.f;
#pragma unroll 4
      for (int j4 = 0; j4 < 16; j4++) {
        float4 d4 = *reinterpret_cast<const float4*>(&s.dx1L[q * 64 + j4 * 4]);
        float4 w4 = *reinterpret_cast<const float4*>(row + j4 * 4);
        p += d4.x * w4.x + d4.y * w4.y + d4.z * w4.z + d4.w * w4.w;
      }
      s.scr[t] = p;
    }
    __syncthreads();
    if (t < R2_DIM)
      g = s.scr[4 * t] + s.scr[4 * t + 1] + s.scr[4 * t + 2] + s.scr[4 * t + 3];
  }
  float r2new = 0.f;
  if (t < R2_DIM) {
    r2new = softt(s.r2L[t] - 0.1f * g, 0.001f);
    s.r2L[t] = r2new;
  }
  zr2_out = !vote_nz((t < R2_DIM) && (r2new != 0.f), s.vz + 0);  // slot0
}

__global__ __launch_bounds__(256) void k_ista(float* __restrict__ ws,
                                              const float* __restrict__ T2,
                                              const float* __restrict__ h1W,
                                              const float* __restrict__ h1b,
                                              const float* __restrict__ lns,
                                              const float* __restrict__ lnb,
                                              const float* __restrict__ h2W,
                                              const float* __restrict__ h2b,
                                              const float* __restrict__ h3W,
                                              const float* __restrict__ h3b,
                                              int tstep) {
  extern __shared__ float dynL[];
  float* gG = dynL;            // 16384 floats, swizzled float4 layout
  float* cS = dynL + 16384;    // 32*129 floats
  __shared__ SMS s;

  const float* Gg = ws + OFF_G;
  const float* U = ws + OFF_U;
  const float* SXg = ws + OFF_SX;
  float* Rg = ws + OFF_R;
  float* R2g = ws + OFF_R2;
  float* Lacc = ws + OFF_LOSS;

  int b = blockIdx.x, t = threadIdx.x;
  int blk = b * T_SZ + tstep;

  if (t < R_DIM) {
    s.uL[t] = U[(size_t)blk * R_DIM + t];
    s.rprevL[t] = Rg[b * R_DIM + t];
  }
  if (t < R2_DIM) s.r2L[t] = R2g[b * R2_DIM + t];
  if (t == 0) { s.sxS = SXg[blk]; s.cst = 0; }
  // stage G into swizzled LDS (row-major source, symmetric matrix)
  for (int p4 = t; p4 < 4096; p4 += 256) {
    int row = p4 >> 5, c = p4 & 31;
    float4 v = *reinterpret_cast<const float4*>(Gg + row * R_DIM + c * 4);
    *reinterpret_cast<float4*>(&gG[gsw(row, c)]) = v;
  }
  float lnsj = lns[t], lnbj = lnb[t], h1bj = h1b[t], h2bj = h2b[t];
  __syncthreads();
  bool zr2 = !vote_nz((t < R2_DIM) && (s.r2L[t] != 0.f), s.vz + 0);

  float xhatj, aj, rstd;
  bool zw;
  hyp_fwd(s, h1W, h2W, h3W, h3b, h1bj, h2bj, lnsj, lnbj, zr2, zw, xhatj, aj, rstd);

  // warm start r0 = w . c  (exactly 0 when w == 0)
  if (zw) {
    if (t < R_DIM) s.rL[t] = 0.f;
  } else {
    ensure_c(s, cS, T2, t);
    if (t < R_DIM) s.rL[t] = rhat_at(s, cS, t);
  }
  __syncthreads();

  for (int it = 0; it < MAX_IT; it++) {
    // [A] e = r - r_hat ; partial r@G (all 256 threads, 64 MACs each)
    if (!zw) ensure_c(s, cS, T2, t);
    if (t < R_DIM) s.eL[t] = zw ? s.rL[t] : (s.rL[t] - rhat_at(s, cS, t));
    {
      int i = t & 127, hh = (t >> 7) * 16;
      float g = 0.f;
#pragma unroll
      for (int cc = 0; cc < 16; cc++) {
        int c = hh + cc;
        float4 g4 = *reinterpret_cast<const float4*>(&gG[gsw(i, c)]);
        float4 r4 = *reinterpret_cast<const float4*>(&s.rL[c * 4]);
        g += g4.x * r4.x + g4.y * r4.y + g4.z * r4.z + g4.w * r4.w;
      }
      s.scr[t] = g;
    }
    __syncthreads();
    // [B] proximal update of r (grads at old r)
    if (t < R_DIM) {
      float g = s.scr[t] + s.scr[t + R_DIM];
      float gr = 2.f * (g - s.uL[t]) + 2.f * s.eL[t];
      s.rL[t] = softt(s.rL[t] - 0.1f * gr, 0.001f);
    }
    hyp_bwd(s, cS, T2, h1W, h2W, h3W, zw, zr2, xhatj, aj, rstd, lnsj);
    hyp_fwd(s, h1W, h2W, h3W, h3b, h1bj, h2bj, lnsj, lnbj, zr2, zw, xhatj, aj, rstd);
  }

  // final r_hat with w(r2_final); losses via quadratic form
  if (!zw) ensure_c(s, cS, T2, t);
  if (t < R_DIM) s.rhfL[t] = zw ? 0.f : rhat_at(s, cS, t);
  __syncthreads();
  float c0 = 0.f, c1 = 0.f, c2 = 0.f;
  if (t < R_DIM) {
    float g = 0.f;
#pragma unroll
    for (int c = 0; c < 32; c++) {
      float4 g4 = *reinterpret_cast<const float4*>(&gG[gsw(t, c)]);
      float4 r4 = *reinterpret_cast<const float4*>(&s.rhfL[c * 4]);
      g += g4.x * r4.x + g4.y * r4.y + g4.z * r4.z + g4.w * r4.w;
    }
    float v = s.rhfL[t];
    c0 = v * g - 2.f * v * s.uL[t];
    float e = s.rL[t] - v;
    c2 = e * e;
  } else {
    int i = t - R_DIM;
    float g = 0.f;
#pragma unroll
    for (int c = 0; c < 32; c++) {
      float4 g4 = *reinterpret_cast<const float4*>(&gG[gsw(i, c)]);
      float4 r4 = *reinterpret_cast<const float4*>(&s.rL[c * 4]);
      g += g4.x * r4.x + g4.y * r4.y + g4.z * r4.z + g4.w * r4.w;
    }
    float v = s.rL[i];
    c1 = v * g - 2.f * v * s.uL[i];
  }
  float2 s01 = blk_sum2(c0, c1, s.red);
  float2 s2x = blk_sum2(c2, 0.f, s.red);
  if (t == 0) {
    atomicAdd(&Lacc[0], s01.x + s.sxS);  // spat_rhat
    atomicAdd(&Lacc[1], s01.y + s.sxS);  // spat_rbar
    atomicAdd(&Lacc[2], s2x.x);          // temp_loss
  }
  if (t < R_DIM) Rg[b * R_DIM + t] = s.rL[t];
  if (t < R2_DIM) R2g[b * R2_DIM + t] = s.r2L[t];
}

// ---------------- finalize: fp32 outputs --------------------------------------
__global__ __launch_bounds__(256) void k_final(const float* __restrict__ ws,
                                               float* __restrict__ out) {
  int idx = blockIdx.x * 256 + threadIdx.x;
  const int n = 3 + B_SZ * R_DIM + B_SZ * R2_DIM;
  if (idx >= n) return;
  float v;
  if (idx < 3) v = ws[OFF_LOSS + idx] * (1.f / (B_SZ * T_SZ));
  else if (idx < 3 + B_SZ * R_DIM) v = ws[OFF_R + (idx - 3)];
  else v = ws[OFF_R2 + (idx - 3 - B_SZ * R_DIM)];
  out[idx] = v;
}

extern "C" void kernel_launch(void* const* d_in, const int* in_sizes, int n_in,
                              void* d_out, int out_size, void* d_ws, size_t ws_size,
                              hipStream_t stream) {
  const float* X = (const float*)d_in[0];
  const float* decW = (const float*)d_in[1];
  const float* decb = (const float*)d_in[2];
  const float* temporal = (const float*)d_in[3];
  const float* h1W = (const float*)d_in[4];
  const float* h1b = (const float*)d_in[5];
  const float* lns = (const float*)d_in[6];
  const float* lnb = (const float*)d_in[7];
  const float* h2W = (const float*)d_in[8];
  const float* h2b = (const float*)d_in[9];
  const float* h3W = (const float*)d_in[10];
  const float* h3b = (const float*)d_in[11];
  float* ws = (float*)d_ws;  // ~2.3 MiB used
  float* out = (float*)d_out;

  const int dyn_bytes = (16384 + MIX * 129) * (int)sizeof(float);  // 82,048 B
  static int attr_set = -1;
  (void)attr_set;
  hipFuncSetAttribute((const void*)k_ista,
                      hipFuncAttributeMaxDynamicSharedMemorySize, dyn_bytes);

  k_init<<<64, 256, 0, stream>>>(ws);
  k_prepG<<<128, 128, 0, stream>>>(decW, ws + OFF_G);
  k_prepU<<<512, 128, 0, stream>>>(X, decb, decW, ws + OFF_U, ws + OFF_SX);
  for (int t = 0; t < T_SZ; t++) {
    k_ista<<<B_SZ, 256, dyn_bytes, stream>>>(ws, temporal, h1W, h1b, lns, lnb,
                                             h2W, h2b, h3W, h3b, t);
  }
  k_final<<<193, 256, 0, stream>>>(ws, out);
}

// Round 4
// 391.048 us; speedup vs baseline: 10.3764x; 1.8502x over previous
//
#include <hip/hip_runtime.h>
#include <cstdint>
#include <cstddef>

// Problem constants
#define R_DIM   128
#define R2_DIM  64
#define MIX     32
#define IN_DIM  512
#define HID     256
#define B_SZ    256
#define T_SZ    16
#define MAX_IT  12

// Workspace layout (float offsets)
#define OFF_GQ   0           // 16384  (Gq packed layout)
#define OFF_U    16384       // 4096*128
#define OFF_SX   540672      // 4096
#define OFF_LOSS 544768      // 3

__device__ __forceinline__ float softt(float v, float lam) {
  float a = fabsf(v) - lam;
  return a > 0.f ? (v > 0.f ? a : -a) : 0.f;
}

__device__ __forceinline__ float rdlane(float v, int lane) {
  int i = __builtin_amdgcn_readlane(__float_as_int(v), lane);
  return __int_as_float(i);
}

__device__ __forceinline__ float wsum_all(float v) {  // result on all lanes
#pragma unroll
  for (int off = 32; off; off >>= 1) v += __shfl_xor(v, off, 64);
  return v;
}

__device__ __forceinline__ float wsum(float v) {  // result on lane 0
#pragma unroll
  for (int off = 32; off; off >>= 1) v += __shfl_down(v, off, 64);
  return v;
}

// ---------------- init: zero loss accumulators --------------------------------
__global__ __launch_bounds__(64) void k_init(float* ws) {
  if (threadIdx.x < 3) ws[OFF_LOSS + threadIdx.x] = 0.f;
}

// ---------------- Gq = dec_W @ dec_W^T in packed fl4 layout -------------------
// fl4 at index (jj*128 + ph*64 + l) = (G[ra][l], G[ra][l+64], G[ra+1][l], G[ra+1][l+64])
// with ra = 4*jj + 2*ph.  (jj = 0..31, ph = 0..1, l = 0..63)
__global__ __launch_bounds__(128) void k_prepG(const float* __restrict__ decW,
                                               float* __restrict__ Gq) {
  __shared__ __align__(16) float dw[4][IN_DIM];
  int jj = blockIdx.x;  // 0..31
  int t = threadIdx.x;
  for (int p = t; p < 4 * IN_DIM / 4; p += 128) {  // fl4 units
    int rr = p >> 7, c4 = p & 127;
    *(float4*)&dw[rr][c4 * 4] =
        *(const float4*)(decW + (size_t)(4 * jj + rr) * IN_DIM + c4 * 4);
  }
  __syncthreads();
  int l = t & 63, ph = t >> 6;
  const float* rowl = decW + (size_t)l * IN_DIM;
  const float* rowl64 = decW + (size_t)(l + 64) * IN_DIM;
  float aa = 0.f, ab = 0.f, ba = 0.f, bb = 0.f;
  for (int c4 = 0; c4 < IN_DIM / 4; c4++) {
    float4 wl = *(const float4*)(rowl + c4 * 4);
    float4 wl64 = *(const float4*)(rowl64 + c4 * 4);
    float4 a4 = *(const float4*)&dw[2 * ph][c4 * 4];
    float4 b4 = *(const float4*)&dw[2 * ph + 1][c4 * 4];
    aa += wl.x * a4.x + wl.y * a4.y + wl.z * a4.z + wl.w * a4.w;
    ab += wl64.x * a4.x + wl64.y * a4.y + wl64.z * a4.z + wl64.w * a4.w;
    ba += wl.x * b4.x + wl.y * b4.y + wl.z * b4.z + wl.w * b4.w;
    bb += wl64.x * b4.x + wl64.y * b4.y + wl64.z * b4.z + wl64.w * b4.w;
  }
  *(float4*)(Gq + (size_t)(jj * 128 + ph * 64 + l) * 4) = make_float4(aa, ab, ba, bb);
}

// ---------------- u[b,t,:] = (x - dec_b) @ dec_W^T ; sx[b,t] = ||x-dec_b||^2 --
__global__ __launch_bounds__(128) void k_prepU(const float* __restrict__ X,
                                               const float* __restrict__ decb,
                                               const float* __restrict__ decW,
                                               float* __restrict__ U,
                                               float* __restrict__ SX) {
  __shared__ __align__(16) float xm[8][IN_DIM];
  __shared__ float scr[128];
  int blk0 = blockIdx.x * 8;
  for (int p = threadIdx.x; p < 8 * IN_DIM / 4; p += 128) {
    int g = p >> 7, c4 = p & 127;
    float4 xv = *reinterpret_cast<const float4*>(X + (size_t)(blk0 + g) * IN_DIM + c4 * 4);
    float4 bv = *reinterpret_cast<const float4*>(decb + c4 * 4);
    xm[g][c4 * 4 + 0] = xv.x - bv.x;
    xm[g][c4 * 4 + 1] = xv.y - bv.y;
    xm[g][c4 * 4 + 2] = xv.z - bv.z;
    xm[g][c4 * 4 + 3] = xv.w - bv.w;
  }
  __syncthreads();
  {
    int g = threadIdx.x >> 4, l16 = threadIdx.x & 15;
    float s = 0.f;
    for (int dd = 0; dd < 32; dd++) { float v = xm[g][l16 * 32 + dd]; s += v * v; }
    scr[threadIdx.x] = s;
  }
  __syncthreads();
  if (threadIdx.x < 8) {
    float s = 0.f;
    for (int h = 0; h < 16; h++) s += scr[threadIdx.x * 16 + h];
    SX[blk0 + threadIdx.x] = s;
  }
  int i = threadIdx.x;
  const float* wr = decW + (size_t)i * IN_DIM;
  float acc[8] = {0.f, 0.f, 0.f, 0.f, 0.f, 0.f, 0.f, 0.f};
  for (int d4 = 0; d4 < IN_DIM / 4; d4++) {
    float4 w4 = *reinterpret_cast<const float4*>(wr + d4 * 4);
#pragma unroll
    for (int g = 0; g < 8; g++) {
      float4 xv = *reinterpret_cast<const float4*>(&xm[g][d4 * 4]);
      acc[g] += w4.x * xv.x + w4.y * xv.y + w4.z * xv.z + w4.w * xv.w;
    }
  }
  for (int g = 0; g < 8; g++) U[(size_t)(blk0 + g) * R_DIM + i] = acc[g];
}

// ---------------- persistent main kernel: one wave per batch element ----------
// LDS floats: Gq 16384 | cS 4128 | aL 256 | x2L 256 | dx1L 256 | dx2L 256
//           | wL 32 | dx3L 32 | eL 128 | rpL 128   = 21856 (87,424 B)
__global__ __launch_bounds__(64, 1) void k_main(
    float* __restrict__ ws, const float* __restrict__ T2,
    const float* __restrict__ h1W, const float* __restrict__ h1b,
    const float* __restrict__ lns, const float* __restrict__ lnb,
    const float* __restrict__ h2W, const float* __restrict__ h2b,
    const float* __restrict__ h3W, const float* __restrict__ h3b,
    float* __restrict__ out) {
  extern __shared__ __align__(16) float L[];
  float* Gq = L;                // 16384
  float* cS = L + 16384;        // 4128 (stride 129)
  float* aL = cS + 4128;        // 256
  float* x2L = aL + 256;        // 256
  float* dx1L = x2L + 256;      // 256
  float* dx2L = dx1L + 256;     // 256
  float* wL = dx2L + 256;       // 32
  float* dx3L = wL + 32;        // 32
  float* eL = dx3L + 32;        // 128
  float* rpL = eL + 128;        // 128

  const int l = threadIdx.x;
  const int b = blockIdx.x;
  const float* Ug = ws + OFF_U;
  const float* SXg = ws + OFF_SX;
  float* Lacc = ws + OFF_LOSS;

  // stage Gq once (single wave: no barrier needed, lgkmcnt handles ordering)
  {
    const float4* src = (const float4*)(ws + OFF_GQ);
    float4* dst = (float4*)Gq;
    for (int i = 0; i < 64; i++) dst[i * 64 + l] = src[i * 64 + l];
  }
  float lnsv[4], lnbv[4], h1bv[4], h2bv[4];
#pragma unroll
  for (int q = 0; q < 4; q++) {
    lnsv[q] = lns[l + 64 * q];
    lnbv[q] = lnb[l + 64 * q];
    h1bv[q] = h1b[l + 64 * q];
    h2bv[q] = h2b[l + 64 * q];
  }
  float h3bv = (l < 32) ? h3b[l] : 0.f;

  float r0 = 0.f, r1 = 0.f, r2v = 0.f;
  bool zr2 = true, fwdv = false, zw = true, rhv = false, cst = false;
  float xh[4] = {0.f, 0.f, 0.f, 0.f}, av[4] = {0.f, 0.f, 0.f, 0.f}, rstd = 0.f;
  float rh0 = 0.f, rh1 = 0.f;
  float lc0 = 0.f, lc1 = 0.f, lc2 = 0.f, sxa = 0.f;

  // c[m,i] for current r_prev (lazy, per step)
  auto ensure_c = [&]() {
    if (cst) return;
    for (int p = l; p < MIX * R_DIM; p += 64) {
      const float* row = T2 + (size_t)p * R_DIM;
      float acc = 0.f;
      for (int j4 = 0; j4 < R_DIM / 4; j4++) {
        float4 w4 = *(const float4*)(row + j4 * 4);
        float4 r4 = *(const float4*)(&rpL[j4 * 4]);
        acc += w4.x * r4.x + w4.y * r4.y + w4.z * r4.z + w4.w * r4.w;
      }
      cS[(p >> 7) * 129 + (p & 127)] = acc;
    }
    cst = true;
  };

  auto rhat_comp = [&]() {
    float a0 = 0.f, a1 = 0.f;
#pragma unroll
    for (int m4 = 0; m4 < 8; m4++) {
      float4 w4 = *(const float4*)&wL[m4 * 4];
      int mb = m4 * 4;
      a0 += w4.x * cS[(mb + 0) * 129 + l] + w4.y * cS[(mb + 1) * 129 + l] +
            w4.z * cS[(mb + 2) * 129 + l] + w4.w * cS[(mb + 3) * 129 + l];
      a1 += w4.x * cS[(mb + 0) * 129 + 64 + l] + w4.y * cS[(mb + 1) * 129 + 64 + l] +
            w4.z * cS[(mb + 2) * 129 + 64 + l] + w4.w * cS[(mb + 3) * 129 + 64 + l];
    }
    rh0 = a0; rh1 = a1;
  };

  // g_i = sum_j r_j G[j][i], outputs at i=l and i=l+64; r broadcast via readlane
  auto matvec = [&](float& g0, float& g1, float a0, float a1) {
    g0 = 0.f; g1 = 0.f;
#pragma unroll
    for (int jj = 0; jj < 32; jj++) {
      float rs = (jj < 16) ? a0 : a1;
      int jb = (jj & 15) * 4;
      float s0 = rdlane(rs, jb + 0), s1 = rdlane(rs, jb + 1);
      float s2 = rdlane(rs, jb + 2), s3 = rdlane(rs, jb + 3);
      float4 A = *(const float4*)&Gq[(jj * 128 + l) * 4];
      float4 Bv = *(const float4*)&Gq[(jj * 128 + 64 + l) * 4];
      g0 += s0 * A.x + s1 * A.z + s2 * Bv.x + s3 * Bv.z;
      g1 += s0 * A.y + s1 * A.w + s2 * Bv.y + s3 * Bv.w;
    }
  };

  auto hyp_fwd = [&]() {
    float x1[4];
#pragma unroll
    for (int q = 0; q < 4; q++) x1[q] = h1bv[q];
    if (!zr2) {
      for (int k = 0; k < R2_DIM; k++) {
        float rk = rdlane(r2v, k);   // uniform -> scalar branch
        if (rk != 0.f) {
#pragma unroll
          for (int q = 0; q < 4; q++) x1[q] += rk * h1W[k * HID + l + 64 * q];
        }
      }
    }
    float s1 = x1[0] + x1[1] + x1[2] + x1[3];
    float s2 = x1[0] * x1[0] + x1[1] * x1[1] + x1[2] * x1[2] + x1[3] * x1[3];
    s1 = wsum_all(s1); s2 = wsum_all(s2);
    float mu = s1 * (1.f / HID);
    float var = s2 * (1.f / HID) - mu * mu;
    rstd = rsqrtf(var + 1e-6f);
    bool anz = false;
#pragma unroll
    for (int q = 0; q < 4; q++) {
      xh[q] = (x1[q] - mu) * rstd;
      float y = xh[q] * lnsv[q] + lnbv[q];
      av[q] = (y > 0.f) ? y : expm1f(y);
      aL[l + 64 * q] = av[q];
      anz |= (av[q] != 0.f);
    }
    bool za = (__ballot(anz) == 0ull);
    float x2[4];
#pragma unroll
    for (int q = 0; q < 4; q++) x2[q] = h2bv[q];
    if (!za) {
      for (int k4 = 0; k4 < HID / 4; k4++) {
        float4 a4 = *(const float4*)&aL[k4 * 4];
#pragma unroll
        for (int c = 0; c < 4; c++) {
          float ac = (&a4.x)[c];
          int k = k4 * 4 + c;
#pragma unroll
          for (int q = 0; q < 4; q++) x2[q] += ac * h2W[(size_t)k * HID + l + 64 * q];
        }
      }
    }
    bool x2nz = false;
#pragma unroll
    for (int q = 0; q < 4; q++) { x2L[l + 64 * q] = x2[q]; x2nz |= (x2[q] != 0.f); }
    bool zx2 = (__ballot(x2nz) == 0ull);
    int m = l & 31, kh = l >> 5;
    float p = 0.f;
    if (!zx2) {
      for (int kk = 0; kk < 128; kk++) {
        int k = kh * 128 + kk;
        p += x2L[k] * h3W[k * MIX + m];
      }
    }
    p += __shfl_xor(p, 32, 64);
    float wv = 0.f;
    if (l < 32) { wv = fmaxf(h3bv + p, 0.f); wL[l] = wv; }
    zw = (__ballot(wv != 0.f) == 0ull);
  };

  auto hyp_bwd = [&]() -> bool {  // returns "r2 changed"
    bool zd3 = true;
    if (!zw) {
      ensure_c();
      int m = l & 31, ih = l >> 5;
      float p = 0.f;
      for (int ii = 0; ii < 64; ii++) {
        int i = ih * 64 + ii;
        p += eL[i] * cS[m * 129 + i];
      }
      p += __shfl_xor(p, 32, 64);
      float d3 = 0.f;
      if (l < 32) { d3 = (wL[l] > 0.f) ? (-2.f * p) : 0.f; dx3L[l] = d3; }
      zd3 = (__ballot(d3 != 0.f) == 0ull);
    }
    float g = 0.f;
    if (!zd3) {
      float dx2[4] = {0.f, 0.f, 0.f, 0.f};
#pragma unroll
      for (int m4 = 0; m4 < 8; m4++) {
        float4 d4 = *(const float4*)&dx3L[m4 * 4];
#pragma unroll
        for (int q = 0; q < 4; q++) {
          const float* r3 = h3W + (size_t)(l + 64 * q) * MIX + m4 * 4;
          dx2[q] += d4.x * r3[0] + d4.y * r3[1] + d4.z * r3[2] + d4.w * r3[3];
        }
      }
#pragma unroll
      for (int q = 0; q < 4; q++) dx2L[l + 64 * q] = dx2[q];
      float dxh[4];
      float s1 = 0.f, s2 = 0.f;
#pragma unroll
      for (int q = 0; q < 4; q++) {
        float da = 0.f;
        const float* row = h2W + (size_t)(l + 64 * q) * HID;
        for (int k4 = 0; k4 < HID / 4; k4++) {
          float4 w4 = *(const float4*)(row + k4 * 4);
          float4 d4 = *(const float4*)&dx2L[k4 * 4];
          da += w4.x * d4.x + w4.y * d4.y + w4.z * d4.z + w4.w * d4.w;
        }
        float dy = da * (av[q] > 0.f ? 1.f : (av[q] + 1.f));
        dxh[q] = dy * lnsv[q];
        s1 += dxh[q]; s2 += dxh[q] * xh[q];
      }
      s1 = wsum_all(s1); s2 = wsum_all(s2);
#pragma unroll
      for (int q = 0; q < 4; q++) {
        float dx1 = rstd * (dxh[q] - s1 * (1.f / HID) - xh[q] * (s2 * (1.f / HID)));
        dx1L[l + 64 * q] = dx1;
      }
      const float* row1 = h1W + (size_t)l * HID;
      for (int j4 = 0; j4 < HID / 4; j4++) {
        float4 w4 = *(const float4*)(row1 + j4 * 4);
        float4 d4 = *(const float4*)&dx1L[j4 * 4];
        g += w4.x * d4.x + w4.y * d4.y + w4.z * d4.z + w4.w * d4.w;
      }
    }
    float r2n = softt(r2v - 0.1f * g, 0.001f);
    bool ch = (__ballot(r2n != r2v) != 0ull);
    r2v = r2n;
    zr2 = (__ballot(r2n != 0.f) == 0ull);
    return ch;
  };

  // prefetch step 0
  float u0n = Ug[(size_t)(b * T_SZ) * R_DIM + l];
  float u1n = Ug[(size_t)(b * T_SZ) * R_DIM + 64 + l];
  float sxn = SXg[b * T_SZ];

#pragma unroll 1
  for (int t = 0; t < T_SZ; t++) {
    float u0 = u0n, u1 = u1n, sxv = sxn;
    if (t < T_SZ - 1) {
      u0n = Ug[(size_t)(b * T_SZ + t + 1) * R_DIM + l];
      u1n = Ug[(size_t)(b * T_SZ + t + 1) * R_DIM + 64 + l];
      sxn = SXg[b * T_SZ + t + 1];
    }
    rpL[l] = r0; rpL[64 + l] = r1;  // r_prev for c
    cst = false; rhv = false;
    if (!fwdv) { hyp_fwd(); fwdv = true; }
    if (zw) { rh0 = 0.f; rh1 = 0.f; } else { ensure_c(); rhat_comp(); }
    rhv = true;
    // warm start r0 = temp_pred (no threshold)
    r0 = rh0; r1 = rh1;
    bool rzero = zw;
#pragma unroll 1
    for (int it = 0; it < MAX_IT; it++) {
      if (!rhv) {
        if (zw) { rh0 = 0.f; rh1 = 0.f; } else { ensure_c(); rhat_comp(); }
        rhv = true;
      }
      float e0 = r0 - rh0, e1 = r1 - rh1;
      float g0 = 0.f, g1 = 0.f;
      if (!rzero) matvec(g0, g1, r0, r1);
      rzero = false;
      r0 = softt(r0 - 0.2f * (g0 - u0 + e0), 0.001f);
      r1 = softt(r1 - 0.2f * (g1 - u1 + e1), 0.001f);
      if (!(zw && zr2)) {  // else r2 provably unchanged (all-zero fixed point)
        eL[l] = e0; eL[64 + l] = e1;
        bool ch = hyp_bwd();
        if (ch) fwdv = false;
        if (!fwdv) { hyp_fwd(); fwdv = true; rhv = false; }
      }
    }
    // epilogue losses
    if (!rhv) {
      if (zw) { rh0 = 0.f; rh1 = 0.f; } else { ensure_c(); rhat_comp(); }
      rhv = true;
    }
    float gb0, gb1;
    matvec(gb0, gb1, r0, r1);
    lc1 += r0 * gb0 - 2.f * r0 * u0 + r1 * gb1 - 2.f * r1 * u1;
    if (zw) {
      lc2 += r0 * r0 + r1 * r1;  // rhat = 0; c0 contribution = 0
    } else {
      float gh0, gh1;
      matvec(gh0, gh1, rh0, rh1);
      lc0 += rh0 * gh0 - 2.f * rh0 * u0 + rh1 * gh1 - 2.f * rh1 * u1;
      float d0 = r0 - rh0, d1 = r1 - rh1;
      lc2 += d0 * d0 + d1 * d1;
    }
    if (l == 0) sxa += sxv;
  }

  float t0 = wsum(lc0), t1 = wsum(lc1), t2 = wsum(lc2);
  if (l == 0) {
    atomicAdd(&Lacc[0], t0 + sxa);
    atomicAdd(&Lacc[1], t1 + sxa);
    atomicAdd(&Lacc[2], t2);
  }
  out[3 + b * R_DIM + l] = r0;
  out[3 + b * R_DIM + 64 + l] = r1;
  out[3 + B_SZ * R_DIM + b * R2_DIM + l] = r2v;
}

// ---------------- finalize: scale the 3 losses --------------------------------
__global__ __launch_bounds__(64) void k_final(const float* __restrict__ ws,
                                              float* __restrict__ out) {
  if (threadIdx.x < 3)
    out[threadIdx.x] = ws[OFF_LOSS + threadIdx.x] * (1.f / (B_SZ * T_SZ));
}

extern "C" void kernel_launch(void* const* d_in, const int* in_sizes, int n_in,
                              void* d_out, int out_size, void* d_ws, size_t ws_size,
                              hipStream_t stream) {
  const float* X = (const float*)d_in[0];
  const float* decW = (const float*)d_in[1];
  const float* decb = (const float*)d_in[2];
  const float* temporal = (const float*)d_in[3];
  const float* h1W = (const float*)d_in[4];
  const float* h1b = (const float*)d_in[5];
  const float* lns = (const float*)d_in[6];
  const float* lnb = (const float*)d_in[7];
  const float* h2W = (const float*)d_in[8];
  const float* h2b = (const float*)d_in[9];
  const float* h3W = (const float*)d_in[10];
  const float* h3b = (const float*)d_in[11];
  float* ws = (float*)d_ws;  // ~2.1 MiB used
  float* out = (float*)d_out;

  const int dyn_bytes = 21856 * (int)sizeof(float);  // 87,424 B
  hipFuncSetAttribute((const void*)k_main,
                      hipFuncAttributeMaxDynamicSharedMemorySize, dyn_bytes);

  k_init<<<1, 64, 0, stream>>>(ws);
  k_prepG<<<32, 128, 0, stream>>>(decW, ws + OFF_GQ);
  k_prepU<<<512, 128, 0, stream>>>(X, decb, decW, ws + OFF_U, ws + OFF_SX);
  k_main<<<B_SZ, 64, dyn_bytes, stream>>>(ws, temporal, h1W, h1b, lns, lnb,
                                          h2W, h2b, h3W, h3b, out);
  k_final<<<1, 64, 0, stream>>>(ws, out);
}

// Round 5
// 341.189 us; speedup vs baseline: 11.8928x; 1.1461x over previous
//
#include <hip/hip_runtime.h>
#include <cstdint>
#include <cstddef>

// Problem constants
#define R_DIM   128
#define R2_DIM  64
#define MIX     32
#define IN_DIM  512
#define HID     256
#define B_SZ    256
#define T_SZ    16
#define MAX_IT  12

// Workspace layout (float offsets)
#define OFF_G    0           // 16384 (row-major 128x128)
#define OFF_U    16384       // 4096*128
#define OFF_SX   540672      // 4096
#define OFF_LOSS 544768      // 3

__device__ __forceinline__ float softt(float v, float lam) {
  float a = fabsf(v) - lam;
  return a > 0.f ? (v > 0.f ? a : -a) : 0.f;
}

__device__ __forceinline__ float rdlane(float v, int lane) {
  int i = __builtin_amdgcn_readlane(__float_as_int(v), lane);
  return __int_as_float(i);
}

__device__ __forceinline__ float wsum_all(float v) {
#pragma unroll
  for (int off = 32; off; off >>= 1) v += __shfl_xor(v, off, 64);
  return v;
}

__device__ __forceinline__ float wsum(float v) {  // result on lane 0
#pragma unroll
  for (int off = 32; off; off >>= 1) v += __shfl_down(v, off, 64);
  return v;
}

// ---------------- init: zero loss accumulators --------------------------------
__global__ __launch_bounds__(64) void k_init(float* ws) {
  if (threadIdx.x < 3) ws[OFF_LOSS + threadIdx.x] = 0.f;
}

// ---------------- G = dec_W @ dec_W^T (128x128 row-major, symmetric) ----------
__global__ __launch_bounds__(128) void k_prepG(const float* __restrict__ decW,
                                               float* __restrict__ G) {
  __shared__ __align__(16) float rowi[IN_DIM];
  int i = blockIdx.x;
  for (int d = threadIdx.x; d < IN_DIM; d += 128) rowi[d] = decW[i * IN_DIM + d];
  __syncthreads();
  int j = threadIdx.x;
  const float* wr = decW + (size_t)j * IN_DIM;
  float acc = 0.f;
  for (int d4 = 0; d4 < IN_DIM / 4; d4++) {
    float4 w4 = *reinterpret_cast<const float4*>(wr + d4 * 4);
    float4 r4 = *reinterpret_cast<const float4*>(&rowi[d4 * 4]);
    acc += w4.x * r4.x + w4.y * r4.y + w4.z * r4.z + w4.w * r4.w;
  }
  G[i * R_DIM + j] = acc;
}

// ---------------- u[b,t,:] = (x - dec_b) @ dec_W^T ; sx[b,t] = ||x-dec_b||^2 --
// 16 (b,t) rows per block (32 KB LDS) to amortize the dec_W stream.
__global__ __launch_bounds__(128) void k_prepU(const float* __restrict__ X,
                                               const float* __restrict__ decb,
                                               const float* __restrict__ decW,
                                               float* __restrict__ U,
                                               float* __restrict__ SX) {
  __shared__ __align__(16) float xm[16][IN_DIM];
  __shared__ float scr[128];
  int blk0 = blockIdx.x * 16;
  for (int p = threadIdx.x; p < 16 * IN_DIM / 4; p += 128) {
    int g = p >> 7, c4 = p & 127;
    float4 xv = *reinterpret_cast<const float4*>(X + (size_t)(blk0 + g) * IN_DIM + c4 * 4);
    float4 bv = *reinterpret_cast<const float4*>(decb + c4 * 4);
    xm[g][c4 * 4 + 0] = xv.x - bv.x;
    xm[g][c4 * 4 + 1] = xv.y - bv.y;
    xm[g][c4 * 4 + 2] = xv.z - bv.z;
    xm[g][c4 * 4 + 3] = xv.w - bv.w;
  }
  __syncthreads();
  {  // sx: 8 threads/row, 64 elems each
    int g = threadIdx.x >> 3, q = threadIdx.x & 7;
    float s = 0.f;
    for (int dd = 0; dd < 64; dd++) { float v = xm[g][q * 64 + dd]; s += v * v; }
    scr[threadIdx.x] = s;
  }
  __syncthreads();
  if (threadIdx.x < 16) {
    float s = 0.f;
#pragma unroll
    for (int h = 0; h < 8; h++) s += scr[threadIdx.x * 8 + h];
    SX[blk0 + threadIdx.x] = s;
  }
  int i = threadIdx.x;
  const float* wr = decW + (size_t)i * IN_DIM;
  float acc[16];
#pragma unroll
  for (int g = 0; g < 16; g++) acc[g] = 0.f;
  for (int d4 = 0; d4 < IN_DIM / 4; d4++) {
    float4 w4 = *reinterpret_cast<const float4*>(wr + d4 * 4);
#pragma unroll
    for (int g = 0; g < 16; g++) {
      float4 xv = *reinterpret_cast<const float4*>(&xm[g][d4 * 4]);
      acc[g] += w4.x * xv.x + w4.y * xv.y + w4.z * xv.z + w4.w * xv.w;
    }
  }
  for (int g = 0; g < 16; g++) U[(size_t)(blk0 + g) * R_DIM + i] = acc[g];
}

// ---------------- persistent main kernel: one wave per batch element ----------
// G lives in 256 VGPRs/lane (scaled by 0.2). LDS only for cold hypernet path.
// LDS floats: cS 4128 | aL 256 | x2L 256 | dx1L 256 | dx2L 256 | wL 32
//           | dx3L 32 | eL 128 | rpL 128  = 5472 (21,888 B)
__global__ __launch_bounds__(64, 1) void k_main(
    float* __restrict__ ws, const float* __restrict__ T2,
    const float* __restrict__ h1W, const float* __restrict__ h1b,
    const float* __restrict__ lns, const float* __restrict__ lnb,
    const float* __restrict__ h2W, const float* __restrict__ h2b,
    const float* __restrict__ h3W, const float* __restrict__ h3b,
    float* __restrict__ out) {
  extern __shared__ __align__(16) float L[];
  float* cS = L;                // 4128 (stride 129)
  float* aL = cS + 4128;        // 256
  float* x2L = aL + 256;        // 256
  float* dx1L = x2L + 256;      // 256
  float* dx2L = dx1L + 256;     // 256
  float* wL = dx2L + 256;       // 32
  float* dx3L = wL + 32;        // 32
  float* eL = dx3L + 32;        // 128
  float* rpL = eL + 128;        // 128

  const int l = threadIdx.x;
  const int b = blockIdx.x;
  const float* Gg = ws + OFF_G;
  const float* Ug = ws + OFF_U;
  const float* SXg = ws + OFF_SX;
  float* Lacc = ws + OFF_LOSS;

  // Stage G columns l and l+64 into registers, pre-scaled by LR (0.2).
  // Fully unrolled constant indexing -> SROA promotes to 256 VGPRs.
  float Ga[128], Gb[128];
#pragma unroll
  for (int j = 0; j < 128; j++) {
    Ga[j] = 0.2f * Gg[j * R_DIM + l];
    Gb[j] = 0.2f * Gg[j * R_DIM + 64 + l];
  }

  float r0 = 0.f, r1 = 0.f, r2v = 0.f;
  bool zr2 = true, fwdv = false, zw = true, rhv = false, cst = false;
  float xh[4] = {0.f, 0.f, 0.f, 0.f}, av[4] = {0.f, 0.f, 0.f, 0.f}, rstd = 0.f;
  float rh0 = 0.f, rh1 = 0.f;
  float lc0 = 0.f, lc1 = 0.f, lc2 = 0.f, sxa = 0.f;

  // g_sc = 0.2 * (G r): pure VALU, readlane broadcast, 4 accums per output
  auto matvec = [&](float& g0, float& g1, float a0, float a1) {
    float p0[4] = {0.f, 0.f, 0.f, 0.f}, p1[4] = {0.f, 0.f, 0.f, 0.f};
#pragma unroll
    for (int j = 0; j < 128; j++) {
      float rj = rdlane((j < 64) ? a0 : a1, j & 63);
      p0[j & 3] += rj * Ga[j];
      p1[j & 3] += rj * Gb[j];
    }
    g0 = (p0[0] + p0[1]) + (p0[2] + p0[3]);
    g1 = (p1[0] + p1[1]) + (p1[2] + p1[3]);
  };

  // ---- cold hypernet machinery (LDS-based; only runs when w or r2 nonzero) --
  auto ensure_c = [&]() {
    if (cst) return;
    for (int p = l; p < MIX * R_DIM; p += 64) {
      const float* row = T2 + (size_t)p * R_DIM;
      float acc = 0.f;
      for (int j4 = 0; j4 < R_DIM / 4; j4++) {
        float4 w4 = *(const float4*)(row + j4 * 4);
        float4 r4 = *(const float4*)(&rpL[j4 * 4]);
        acc += w4.x * r4.x + w4.y * r4.y + w4.z * r4.z + w4.w * r4.w;
      }
      cS[(p >> 7) * 129 + (p & 127)] = acc;
    }
    cst = true;
  };

  auto rhat_comp = [&]() {
    float a0 = 0.f, a1 = 0.f;
#pragma unroll
    for (int m4 = 0; m4 < 8; m4++) {
      float4 w4 = *(const float4*)&wL[m4 * 4];
      int mb = m4 * 4;
      a0 += w4.x * cS[(mb + 0) * 129 + l] + w4.y * cS[(mb + 1) * 129 + l] +
            w4.z * cS[(mb + 2) * 129 + l] + w4.w * cS[(mb + 3) * 129 + l];
      a1 += w4.x * cS[(mb + 0) * 129 + 64 + l] + w4.y * cS[(mb + 1) * 129 + 64 + l] +
            w4.z * cS[(mb + 2) * 129 + 64 + l] + w4.w * cS[(mb + 3) * 129 + 64 + l];
    }
    rh0 = a0; rh1 = a1;
  };

  auto hyp_fwd = [&]() {
    float x1[4];
#pragma unroll
    for (int q = 0; q < 4; q++) x1[q] = h1b[l + 64 * q];
    if (!zr2) {
      for (int k = 0; k < R2_DIM; k++) {
        float rk = rdlane(r2v, k);
        if (rk != 0.f) {
#pragma unroll
          for (int q = 0; q < 4; q++) x1[q] += rk * h1W[k * HID + l + 64 * q];
        }
      }
    }
    float s1 = x1[0] + x1[1] + x1[2] + x1[3];
    float s2 = x1[0] * x1[0] + x1[1] * x1[1] + x1[2] * x1[2] + x1[3] * x1[3];
    s1 = wsum_all(s1); s2 = wsum_all(s2);
    float mu = s1 * (1.f / HID);
    float var = s2 * (1.f / HID) - mu * mu;
    rstd = rsqrtf(var + 1e-6f);
    bool anz = false;
#pragma unroll
    for (int q = 0; q < 4; q++) {
      xh[q] = (x1[q] - mu) * rstd;
      float y = xh[q] * lns[l + 64 * q] + lnb[l + 64 * q];
      av[q] = (y > 0.f) ? y : expm1f(y);
      aL[l + 64 * q] = av[q];
      anz |= (av[q] != 0.f);
    }
    bool za = (__ballot(anz) == 0ull);
    float x2[4];
#pragma unroll
    for (int q = 0; q < 4; q++) x2[q] = h2b[l + 64 * q];
    if (!za) {
      for (int k4 = 0; k4 < HID / 4; k4++) {
        float4 a4 = *(const float4*)&aL[k4 * 4];
#pragma unroll
        for (int c = 0; c < 4; c++) {
          float ac = (&a4.x)[c];
          int k = k4 * 4 + c;
#pragma unroll
          for (int q = 0; q < 4; q++) x2[q] += ac * h2W[(size_t)k * HID + l + 64 * q];
        }
      }
    }
    bool x2nz = false;
#pragma unroll
    for (int q = 0; q < 4; q++) { x2L[l + 64 * q] = x2[q]; x2nz |= (x2[q] != 0.f); }
    bool zx2 = (__ballot(x2nz) == 0ull);
    int m = l & 31, kh = l >> 5;
    float p = 0.f;
    if (!zx2) {
      for (int kk = 0; kk < 128; kk++) {
        int k = kh * 128 + kk;
        p += x2L[k] * h3W[k * MIX + m];
      }
    }
    p += __shfl_xor(p, 32, 64);
    float wv = 0.f;
    if (l < 32) { wv = fmaxf(h3b[l] + p, 0.f); wL[l] = wv; }
    zw = (__ballot(wv != 0.f) == 0ull);
  };

  auto hyp_bwd = [&]() -> bool {  // returns "r2 changed"
    bool zd3 = true;
    if (!zw) {
      ensure_c();
      int m = l & 31, ih = l >> 5;
      float p = 0.f;
      for (int ii = 0; ii < 64; ii++) {
        int i = ih * 64 + ii;
        p += eL[i] * cS[m * 129 + i];
      }
      p += __shfl_xor(p, 32, 64);
      float d3 = 0.f;
      if (l < 32) { d3 = (wL[l] > 0.f) ? (-2.f * p) : 0.f; dx3L[l] = d3; }
      zd3 = (__ballot(d3 != 0.f) == 0ull);
    }
    float g = 0.f;
    if (!zd3) {
      float dx2[4] = {0.f, 0.f, 0.f, 0.f};
#pragma unroll
      for (int m4 = 0; m4 < 8; m4++) {
        float4 d4 = *(const float4*)&dx3L[m4 * 4];
#pragma unroll
        for (int q = 0; q < 4; q++) {
          const float* r3 = h3W + (size_t)(l + 64 * q) * MIX + m4 * 4;
          dx2[q] += d4.x * r3[0] + d4.y * r3[1] + d4.z * r3[2] + d4.w * r3[3];
        }
      }
#pragma unroll
      for (int q = 0; q < 4; q++) dx2L[l + 64 * q] = dx2[q];
      float dxh[4];
      float s1 = 0.f, s2 = 0.f;
#pragma unroll
      for (int q = 0; q < 4; q++) {
        float da = 0.f;
        const float* row = h2W + (size_t)(l + 64 * q) * HID;
        for (int k4 = 0; k4 < HID / 4; k4++) {
          float4 w4 = *(const float4*)(row + k4 * 4);
          float4 d4 = *(const float4*)&dx2L[k4 * 4];
          da += w4.x * d4.x + w4.y * d4.y + w4.z * d4.z + w4.w * d4.w;
        }
        float dy = da * (av[q] > 0.f ? 1.f : (av[q] + 1.f));
        dxh[q] = dy * lns[l + 64 * q];
        s1 += dxh[q]; s2 += dxh[q] * xh[q];
      }
      s1 = wsum_all(s1); s2 = wsum_all(s2);
#pragma unroll
      for (int q = 0; q < 4; q++) {
        float dx1 = rstd * (dxh[q] - s1 * (1.f / HID) - xh[q] * (s2 * (1.f / HID)));
        dx1L[l + 64 * q] = dx1;
      }
      const float* row1 = h1W + (size_t)l * HID;
      for (int j4 = 0; j4 < HID / 4; j4++) {
        float4 w4 = *(const float4*)(row1 + j4 * 4);
        float4 d4 = *(const float4*)&dx1L[j4 * 4];
        g += w4.x * d4.x + w4.y * d4.y + w4.z * d4.z + w4.w * d4.w;
      }
    }
    float r2n = softt(r2v - 0.1f * g, 0.001f);
    bool ch = (__ballot(r2n != r2v) != 0ull);
    r2v = r2n;
    zr2 = (__ballot(r2n != 0.f) == 0ull);
    return ch;
  };

  // prefetch step 0
  float u0n = Ug[(size_t)(b * T_SZ) * R_DIM + l];
  float u1n = Ug[(size_t)(b * T_SZ) * R_DIM + 64 + l];
  float sxn = SXg[b * T_SZ];

#pragma unroll 1
  for (int t = 0; t < T_SZ; t++) {
    float u0 = u0n, u1 = u1n, sxv = sxn;
    if (t < T_SZ - 1) {
      u0n = Ug[(size_t)(b * T_SZ + t + 1) * R_DIM + l];
      u1n = Ug[(size_t)(b * T_SZ + t + 1) * R_DIM + 64 + l];
      sxn = SXg[b * T_SZ + t + 1];
    }
    float u02_0 = 0.2f * u0, u02_1 = 0.2f * u1;
    rpL[l] = r0; rpL[64 + l] = r1;  // r_prev for c
    cst = false; rhv = false;
    if (!fwdv) { hyp_fwd(); fwdv = true; }
    if (zw) { rh0 = 0.f; rh1 = 0.f; } else { ensure_c(); rhat_comp(); }
    rhv = true;
    // warm start r0 = temp_pred (no threshold)
    r0 = rh0; r1 = rh1;
    bool rzero = zw;
#pragma unroll 1
    for (int it = 0; it < MAX_IT; it++) {
      if (!rhv) {
        if (zw) { rh0 = 0.f; rh1 = 0.f; } else { ensure_c(); rhat_comp(); }
        rhv = true;
      }
      float e0 = r0 - rh0, e1 = r1 - rh1;
      float g0 = 0.f, g1 = 0.f;
      if (!rzero) matvec(g0, g1, r0, r1);
      rzero = false;
      // r <- softt(r - 0.2*(G r) - 0.2*e + 0.2*u, 0.001); g already scaled
      r0 = softt(r0 - g0 - 0.2f * e0 + u02_0, 0.001f);
      r1 = softt(r1 - g1 - 0.2f * e1 + u02_1, 0.001f);
      if (!(zw && zr2)) {  // else r2 provably unchanged (all-zero fixed point)
        eL[l] = e0; eL[64 + l] = e1;
        bool ch = hyp_bwd();
        if (ch) fwdv = false;
        if (!fwdv) { hyp_fwd(); fwdv = true; rhv = false; }
      }
    }
    // epilogue losses (quadratic form; matvec returns 0.2*G v -> rescale by 5)
    if (!rhv) {
      if (zw) { rh0 = 0.f; rh1 = 0.f; } else { ensure_c(); rhat_comp(); }
      rhv = true;
    }
    float gb0, gb1;
    matvec(gb0, gb1, r0, r1);
    lc1 += r0 * (5.f * gb0) - 2.f * r0 * u0 + r1 * (5.f * gb1) - 2.f * r1 * u1;
    if (zw) {
      lc2 += r0 * r0 + r1 * r1;  // rhat = 0; c0 contribution = 0
    } else {
      float gh0, gh1;
      matvec(gh0, gh1, rh0, rh1);
      lc0 += rh0 * (5.f * gh0) - 2.f * rh0 * u0 + rh1 * (5.f * gh1) - 2.f * rh1 * u1;
      float d0 = r0 - rh0, d1 = r1 - rh1;
      lc2 += d0 * d0 + d1 * d1;
    }
    if (l == 0) sxa += sxv;
  }

  float t0 = wsum(lc0), t1 = wsum(lc1), t2 = wsum(lc2);
  if (l == 0) {
    atomicAdd(&Lacc[0], t0 + sxa);
    atomicAdd(&Lacc[1], t1 + sxa);
    atomicAdd(&Lacc[2], t2);
  }
  out[3 + b * R_DIM + l] = r0;
  out[3 + b * R_DIM + 64 + l] = r1;
  out[3 + B_SZ * R_DIM + b * R2_DIM + l] = r2v;
}

// ---------------- finalize: scale the 3 losses --------------------------------
__global__ __launch_bounds__(64) void k_final(const float* __restrict__ ws,
                                              float* __restrict__ out) {
  if (threadIdx.x < 3)
    out[threadIdx.x] = ws[OFF_LOSS + threadIdx.x] * (1.f / (B_SZ * T_SZ));
}

extern "C" void kernel_launch(void* const* d_in, const int* in_sizes, int n_in,
                              void* d_out, int out_size, void* d_ws, size_t ws_size,
                              hipStream_t stream) {
  const float* X = (const float*)d_in[0];
  const float* decW = (const float*)d_in[1];
  const float* decb = (const float*)d_in[2];
  const float* temporal = (const float*)d_in[3];
  const float* h1W = (const float*)d_in[4];
  const float* h1b = (const float*)d_in[5];
  const float* lns = (const float*)d_in[6];
  const float* lnb = (const float*)d_in[7];
  const float* h2W = (const float*)d_in[8];
  const float* h2b = (const float*)d_in[9];
  const float* h3W = (const float*)d_in[10];
  const float* h3b = (const float*)d_in[11];
  float* ws = (float*)d_ws;  // ~2.1 MiB used
  float* out = (float*)d_out;

  const int dyn_bytes = 5472 * (int)sizeof(float);  // 21,888 B
  hipFuncSetAttribute((const void*)k_main,
                      hipFuncAttributeMaxDynamicSharedMemorySize, dyn_bytes);

  k_init<<<1, 64, 0, stream>>>(ws);
  k_prepG<<<128, 128, 0, stream>>>(decW, ws + OFF_G);
  k_prepU<<<256, 128, 0, stream>>>(X, decb, decW, ws + OFF_U, ws + OFF_SX);
  k_main<<<B_SZ, 64, dyn_bytes, stream>>>(ws, temporal, h1W, h1b, lns, lnb,
                                          h2W, h2b, h3W, h3b, out);
  k_final<<<1, 64, 0, stream>>>(ws, out);
}